// Round 10
// baseline (25.380 us; speedup 1.0000x reference)
//
#include <hip/hip_runtime.h>
#include <hip/hip_bf16.h>
#include <math.h>

#define B_ 128
#define S_ 512
#define E_ 64
#define PAD_ 72  // bf16/row in LDS; 36-dword row stride keeps DS ops bank-clean

typedef short bf16x8 __attribute__((ext_vector_type(8)));
typedef float f32x4 __attribute__((ext_vector_type(4)));

__device__ __forceinline__ unsigned short f2b(float f) {
  __hip_bfloat16 h = __float2bfloat16(f);
  unsigned short u;
  __builtin_memcpy(&u, &h, 2);
  return u;
}

// Coalesced 16-row normalize (V only): wave reads rows [rbase,+16) of a [*,64]
// f32 matrix with 4 contiguous 1KB instructions. Lane holds cols [4c,+4) of
// rows i*4+g; sum-sq reduces over the 16 c-lanes; emits bf16 ushort4 to LDS.
__device__ __forceinline__ void norm16_v(const float* __restrict__ src,
                                         const float* __restrict__ cwp,
                                         float w0, int c, int g, int lane,
                                         unsigned short* __restrict__ lds_base) {
  f32x4 x[4];
#pragma unroll
  for (int i = 0; i < 4; ++i) x[i] = *(const f32x4*)(src + i * 256 + lane * 4);
#pragma unroll
  for (int i = 0; i < 4; ++i) {
    float ss = x[i][0] * x[i][0] + x[i][1] * x[i][1] +
               x[i][2] * x[i][2] + x[i][3] * x[i][3];
    ss += __shfl_xor(ss, 1); ss += __shfl_xor(ss, 2);
    ss += __shfl_xor(ss, 4); ss += __shfl_xor(ss, 8);
    float s = (w0 * cwp[i * 4 + g]) / fmaxf(sqrtf(ss), 1e-7f);
    ushort4 o;
    o.x = f2b(x[i][0] * s); o.y = f2b(x[i][1] * s);
    o.z = f2b(x[i][2] * s); o.w = f2b(x[i][3] * s);
    *(ushort4*)(lds_base + (size_t)(i * 4 + g) * PAD_ + c * 4) = o;
  }
}

// Fused, 256 blocks x 1024 thr (16 waves), 1 block/CU. Block = (batch, shalf).
// U is NEVER normalized pre-MFMA: raw-u bf16 A-fragments load straight from
// global (max over n commutes with the positive 1/||u|| scale, applied at the
// epilogue). Phase 1 stages only V (staggered halves; other half under 2a).
__global__ __launch_bounds__(1024) void fused_kernel(
    const float* __restrict__ ue, const float* __restrict__ ve,
    const float* __restrict__ cw, const float* __restrict__ mask,
    const float* __restrict__ pw, const float* __restrict__ pb,
    float* __restrict__ out) {
  __shared__ unsigned short vlds[S_ * PAD_];  // 73728 B
  __shared__ float comb[4][256];              // 4096 B

  // bijective swizzle: sibling blocks (same b, shalf 0/1) share an XCD (bx%8)
  const int bx = blockIdx.x;
  const int b = (bx & 7) * 16 + (bx >> 4);
  const int shalf = (bx >> 3) & 1;

  const int tid = threadIdx.x;
  const int wv = tid >> 6;  // 16 waves
  const int lane = tid & 63;
  const int c = lane & 15;
  const int g = lane >> 4;
  const int ws = wv >> 2;  // s-split (0..3): 64 s-rows
  const int wn = wv & 3;   // n-split (0..3): 4 n-tiles per half

  const float w0 = pw[0];
  const float* __restrict__ vb = ve + (size_t)b * S_ * E_;
  const float* __restrict__ cwb = cw + (size_t)b * S_;
  const float* __restrict__ ub = ue + ((size_t)b * S_ + shalf * 256) * E_;
  const float* __restrict__ mb = mask + (size_t)b * S_;

  const int vown = shalf * 256 + wv * 16;        // own-half V rows (16)
  const int voth = (1 - shalf) * 256 + wv * 16;  // other-half base

  // ---- U: raw bf16 A-fragments direct from global + row recip-norms.
  //      Tile st rows ws*64+st*16+c; lane chunks [8g,+8) and [32+8g,+8).
  bf16x8 a[4][2];
  float rn[4];
#pragma unroll
  for (int st = 0; st < 4; ++st) {
    const float* r_ = ub + (size_t)(ws * 64 + st * 16 + c) * E_;
    f32x4 u0 = *(const f32x4*)(r_ + 8 * g);
    f32x4 u1 = *(const f32x4*)(r_ + 8 * g + 4);
    f32x4 u2 = *(const f32x4*)(r_ + 32 + 8 * g);
    f32x4 u3 = *(const f32x4*)(r_ + 32 + 8 * g + 4);
    float ss = 0.f;
#pragma unroll
    for (int j = 0; j < 4; ++j)
      ss = fmaf(u0[j], u0[j],
           fmaf(u1[j], u1[j], fmaf(u2[j], u2[j], fmaf(u3[j], u3[j], ss))));
    ss += __shfl_xor(ss, 16);  // reduce over the 4 g-lanes sharing the row
    ss += __shfl_xor(ss, 32);
    rn[st] = 1.0f / fmaxf(sqrtf(ss), 1e-7f);
#pragma unroll
    for (int j = 0; j < 4; ++j) {
      a[st][0][j] = (short)f2b(u0[j]); a[st][0][4 + j] = (short)f2b(u1[j]);
      a[st][1][j] = (short)f2b(u2[j]); a[st][1][4 + j] = (short)f2b(u3[j]);
    }
  }

  float pen[8];  // own tiles then other tiles, this wave's columns
#pragma unroll
  for (int j = 0; j < 4; ++j) {
    pen[j] = (mb[(shalf * 16 + wn * 4 + j) * 16 + c] > 0.5f) ? 0.0f : -1e30f;
    pen[4 + j] =
        (mb[((1 - shalf) * 16 + wn * 4 + j) * 16 + c] > 0.5f) ? 0.0f : -1e30f;
  }

  // ---- Phase 1: own-half V only, coalesced ----
  norm16_v(vb + (size_t)vown * E_, cwb + vown, w0, c, g, lane,
           vlds + (size_t)vown * PAD_);

  __syncthreads();  // barrier #1: own V-half ready

  // ---- Other-half V: issue loads now (fly under phase-2a) ----
  const float* psrc = vb + (size_t)voth * E_;
  f32x4 y[4];
#pragma unroll
  for (int i = 0; i < 4; ++i) y[i] = *(const f32x4*)(psrc + i * 256 + lane * 4);
  float cwo[4];
#pragma unroll
  for (int i = 0; i < 4; ++i) cwo[i] = cwb[voth + i * 4 + g];

  float r[4][4];
#pragma unroll
  for (int st = 0; st < 4; ++st)
#pragma unroll
    for (int i = 0; i < 4; ++i) r[st][i] = -INFINITY;

  // ---- Phase-2a: scan OWN half ----
#pragma unroll
  for (int j = 0; j < 4; ++j) {
    const int it = shalf * 16 + wn * 4 + j;
    const unsigned short* vr = vlds + (size_t)(it * 16 + c) * PAD_ + g * 8;
    bf16x8 b0 = *(const bf16x8*)(vr);
    bf16x8 b1 = *(const bf16x8*)(vr + 32);
    f32x4 ci = {pen[j], pen[j], pen[j], pen[j]};
#pragma unroll
    for (int st = 0; st < 4; ++st) {
      f32x4 acc = __builtin_amdgcn_mfma_f32_16x16x32_bf16(a[st][0], b0, ci, 0, 0, 0);
      acc = __builtin_amdgcn_mfma_f32_16x16x32_bf16(a[st][1], b1, acc, 0, 0, 0);
      r[st][0] = fmaxf(r[st][0], acc[0]);
      r[st][1] = fmaxf(r[st][1], acc[1]);
      r[st][2] = fmaxf(r[st][2], acc[2]);
      r[st][3] = fmaxf(r[st][3], acc[3]);
    }
  }

  // ---- Normalize other-half V -> LDS (loads already in flight) ----
#pragma unroll
  for (int i = 0; i < 4; ++i) {
    float ss = y[i][0] * y[i][0] + y[i][1] * y[i][1] +
               y[i][2] * y[i][2] + y[i][3] * y[i][3];
    ss += __shfl_xor(ss, 1); ss += __shfl_xor(ss, 2);
    ss += __shfl_xor(ss, 4); ss += __shfl_xor(ss, 8);
    float s = (w0 * cwo[i]) / fmaxf(sqrtf(ss), 1e-7f);
    ushort4 o;
    o.x = f2b(y[i][0] * s); o.y = f2b(y[i][1] * s);
    o.z = f2b(y[i][2] * s); o.w = f2b(y[i][3] * s);
    *(ushort4*)(vlds + (size_t)(voth + i * 4 + g) * PAD_ + c * 4) = o;
  }

  __syncthreads();  // barrier #2: other V-half ready

  // ---- Phase-2b: scan OTHER half ----
#pragma unroll
  for (int j = 0; j < 4; ++j) {
    const int it = (1 - shalf) * 16 + wn * 4 + j;
    const unsigned short* vr = vlds + (size_t)(it * 16 + c) * PAD_ + g * 8;
    bf16x8 b0 = *(const bf16x8*)(vr);
    bf16x8 b1 = *(const bf16x8*)(vr + 32);
    f32x4 ci = {pen[4 + j], pen[4 + j], pen[4 + j], pen[4 + j]};
#pragma unroll
    for (int st = 0; st < 4; ++st) {
      f32x4 acc = __builtin_amdgcn_mfma_f32_16x16x32_bf16(a[st][0], b0, ci, 0, 0, 0);
      acc = __builtin_amdgcn_mfma_f32_16x16x32_bf16(a[st][1], b1, acc, 0, 0, 0);
      r[st][0] = fmaxf(r[st][0], acc[0]);
      r[st][1] = fmaxf(r[st][1], acc[1]);
      r[st][2] = fmaxf(r[st][2], acc[2]);
      r[st][3] = fmaxf(r[st][3], acc[3]);
    }
  }

  // ---- Reduce over 16 column-lanes; apply 1/||u|| (commutes with max) ----
#pragma unroll
  for (int st = 0; st < 4; ++st)
#pragma unroll
    for (int i = 0; i < 4; ++i) {
      float v = r[st][i];
      v = fmaxf(v, __shfl_xor(v, 1)); v = fmaxf(v, __shfl_xor(v, 2));
      v = fmaxf(v, __shfl_xor(v, 4)); v = fmaxf(v, __shfl_xor(v, 8));
      // C-row g*4+i's recip-norm lives in lane c==g*4+i (uniform over g)
      float un = __shfl(rn[st], g * 4 + i);
      r[st][i] = v * un;
    }

  if (c == 0) {
#pragma unroll
    for (int st = 0; st < 4; ++st)
#pragma unroll
      for (int i = 0; i < 4; ++i)
        comb[wn][ws * 64 + st * 16 + g * 4 + i] = r[st][i];
  }

  __syncthreads();  // barrier #3

  if (tid < 256) {
    float v = fmaxf(fmaxf(comb[0][tid], comb[1][tid]),
                    fmaxf(comb[2][tid], comb[3][tid]));
    float bias = pb[0];
    out[(size_t)b * S_ + shalf * 256 + tid] =
        (v < -1e27f) ? 0.0f : 1.0f / (1.0f + expf(-(v + bias)));
  }
}

extern "C" void kernel_launch(void* const* d_in, const int* in_sizes, int n_in,
                              void* d_out, int out_size, void* d_ws, size_t ws_size,
                              hipStream_t stream) {
  const float* ue = (const float*)d_in[0];
  const float* ve = (const float*)d_in[1];
  const float* cw = (const float*)d_in[2];
  const float* mask = (const float*)d_in[3];
  const float* pw = (const float*)d_in[4];
  const float* pb = (const float*)d_in[5];
  float* out = (float*)d_out;

  hipLaunchKernelGGL(fused_kernel, dim3(2 * B_), dim3(1024), 0, stream,
                     ue, ve, cw, mask, pw, pb, out);
}

// Round 11
// 19.245 us; speedup vs baseline: 1.3188x; 1.3188x over previous
//
#include <hip/hip_runtime.h>
#include <hip/hip_bf16.h>
#include <math.h>

#define B_ 128
#define S_ 512
#define E_ 64
#define PAD_ 72  // bf16/row in LDS; 36-dword row stride keeps DS ops bank-clean

typedef short bf16x8 __attribute__((ext_vector_type(8)));
typedef float f32x4 __attribute__((ext_vector_type(4)));

__device__ __forceinline__ unsigned short f2b(float f) {
  __hip_bfloat16 h = __float2bfloat16(f);
  unsigned short u;
  __builtin_memcpy(&u, &h, 2);
  return u;
}

// Normalize 16 rows held in coalesced layout (lane: cols [4c,+4) of local row
// i*4+g) and emit bf16 ushort4 to LDS rows [0,16) of lds_base.
__device__ __forceinline__ void norm16_proc(const f32x4 x[4],
                                            const float* __restrict__ sn,
                                            int c, int g,
                                            unsigned short* __restrict__ lds_base) {
#pragma unroll
  for (int i = 0; i < 4; ++i) {
    float ss = x[i][0] * x[i][0] + x[i][1] * x[i][1] +
               x[i][2] * x[i][2] + x[i][3] * x[i][3];
    ss += __shfl_xor(ss, 1); ss += __shfl_xor(ss, 2);
    ss += __shfl_xor(ss, 4); ss += __shfl_xor(ss, 8);
    float s = sn[i] / fmaxf(sqrtf(ss), 1e-7f);
    ushort4 o;
    o.x = f2b(x[i][0] * s); o.y = f2b(x[i][1] * s);
    o.z = f2b(x[i][2] * s); o.w = f2b(x[i][3] * s);
    *(ushort4*)(lds_base + (size_t)(i * 4 + g) * PAD_ + c * 4) = o;
  }
}

// Fused, 256 blocks x 1024 thr (16 waves), 1 block/CU. Block = (batch, shalf).
// ALL global loads (V-own, U, V-other: 12KB/wave) issue in one dense burst at
// kernel start -> one continuous BW stream, processing overlaps via counted
// vmcnt waits. After barrier#1 the other half is already in registers; scan
// runs in a single merged pass over all 512 n.
__global__ __launch_bounds__(1024) void fused_kernel(
    const float* __restrict__ ue, const float* __restrict__ ve,
    const float* __restrict__ cw, const float* __restrict__ mask,
    const float* __restrict__ pw, const float* __restrict__ pb,
    float* __restrict__ out) {
  __shared__ unsigned short vlds[S_ * PAD_];   // 73728 B
  __shared__ unsigned short ulds[256 * PAD_];  // 36864 B
  __shared__ float comb[4][256];               // 4096 B

  // bijective swizzle: sibling blocks (same b, shalf 0/1) share an XCD (bx%8);
  // staggered halves make the pair cover V once between them.
  const int bx = blockIdx.x;
  const int b = (bx & 7) * 16 + (bx >> 4);
  const int shalf = (bx >> 3) & 1;

  const int tid = threadIdx.x;
  const int wv = tid >> 6;  // 16 waves
  const int lane = tid & 63;
  const int c = lane & 15;
  const int g = lane >> 4;
  const int ws = wv >> 2;  // s-split (0..3): 64 s-rows
  const int wn = wv & 3;   // n-split (0..3): 8 n-tiles

  const float w0 = pw[0];
  const float* __restrict__ vb = ve + (size_t)b * S_ * E_;
  const float* __restrict__ cwb = cw + (size_t)b * S_;
  const float* __restrict__ ub = ue + ((size_t)b * S_ + shalf * 256) * E_;
  const float* __restrict__ mb = mask + (size_t)b * S_;

  const int vown = shalf * 256 + wv * 16;        // own-half V rows (16)
  const int voth = (1 - shalf) * 256 + wv * 16;  // other-half rows (16)
  const int urow = wv * 16;                      // U rows (block-local)

  // ---- Issue ALL global loads now: V-own, U, V-other (12 x 1KB/wave) ----
  const float* pvo = vb + (size_t)vown * E_;
  const float* puu = ub + (size_t)urow * E_;
  const float* pvt = vb + (size_t)voth * E_;
  f32x4 xvo[4], xu[4], xvt[4];
#pragma unroll
  for (int i = 0; i < 4; ++i) xvo[i] = *(const f32x4*)(pvo + i * 256 + lane * 4);
#pragma unroll
  for (int i = 0; i < 4; ++i) xu[i] = *(const f32x4*)(puu + i * 256 + lane * 4);
#pragma unroll
  for (int i = 0; i < 4; ++i) xvt[i] = *(const f32x4*)(pvt + i * 256 + lane * 4);

  float sno[4], snt[4], snu[4];
#pragma unroll
  for (int i = 0; i < 4; ++i) {
    sno[i] = w0 * cwb[vown + i * 4 + g];
    snt[i] = w0 * cwb[voth + i * 4 + g];
    snu[i] = 1.0f;
  }
  float pen[8];  // this wave's 8 n-tiles (it = wn*8+j), column c
#pragma unroll
  for (int j = 0; j < 8; ++j)
    pen[j] = (mb[(wn * 8 + j) * 16 + c] > 0.5f) ? 0.0f : -1e30f;

  // ---- Process in issue order (counted vmcnt waits pipeline naturally) ----
  norm16_proc(xvo, sno, c, g, vlds + (size_t)vown * PAD_);
  norm16_proc(xu, snu, c, g, ulds + (size_t)urow * PAD_);

  __syncthreads();  // barrier #1: own V-half + U staged

  // ---- A-fragments from ulds; V-other processed from registers (no global
  //      waits remain) into the untouched half of vlds ----
  const unsigned short* urp = ulds + (size_t)(ws * 64 + c) * PAD_ + g * 8;
  bf16x8 a[4][2];
#pragma unroll
  for (int st = 0; st < 4; ++st) {
    a[st][0] = *(const bf16x8*)(urp + st * 16 * PAD_);
    a[st][1] = *(const bf16x8*)(urp + st * 16 * PAD_ + 32);
  }
  norm16_proc(xvt, snt, c, g, vlds + (size_t)voth * PAD_);

  __syncthreads();  // barrier #2: full V panel ready

  // ---- Merged scan: this wave's 8 n-tiles over all 512 n ----
  float r[4][4];
#pragma unroll
  for (int st = 0; st < 4; ++st)
#pragma unroll
    for (int i = 0; i < 4; ++i) r[st][i] = -INFINITY;

#pragma unroll
  for (int j = 0; j < 8; ++j) {
    const int it = wn * 8 + j;
    const unsigned short* vr = vlds + (size_t)(it * 16 + c) * PAD_ + g * 8;
    bf16x8 b0 = *(const bf16x8*)(vr);
    bf16x8 b1 = *(const bf16x8*)(vr + 32);
    f32x4 ci = {pen[j], pen[j], pen[j], pen[j]};
#pragma unroll
    for (int st = 0; st < 4; ++st) {
      f32x4 acc = __builtin_amdgcn_mfma_f32_16x16x32_bf16(a[st][0], b0, ci, 0, 0, 0);
      acc = __builtin_amdgcn_mfma_f32_16x16x32_bf16(a[st][1], b1, acc, 0, 0, 0);
      r[st][0] = fmaxf(r[st][0], acc[0]);
      r[st][1] = fmaxf(r[st][1], acc[1]);
      r[st][2] = fmaxf(r[st][2], acc[2]);
      r[st][3] = fmaxf(r[st][3], acc[3]);
    }
  }

  // ---- Reduce over 16 column-lanes ----
#pragma unroll
  for (int st = 0; st < 4; ++st)
#pragma unroll
    for (int i = 0; i < 4; ++i) {
      float v = r[st][i];
      v = fmaxf(v, __shfl_xor(v, 1)); v = fmaxf(v, __shfl_xor(v, 2));
      v = fmaxf(v, __shfl_xor(v, 4)); v = fmaxf(v, __shfl_xor(v, 8));
      r[st][i] = v;
    }

  if (c == 0) {
#pragma unroll
    for (int st = 0; st < 4; ++st)
#pragma unroll
      for (int i = 0; i < 4; ++i)
        comb[wn][ws * 64 + st * 16 + g * 4 + i] = r[st][i];
  }

  __syncthreads();  // barrier #3

  if (tid < 256) {
    float v = fmaxf(fmaxf(comb[0][tid], comb[1][tid]),
                    fmaxf(comb[2][tid], comb[3][tid]));
    float bias = pb[0];
    out[(size_t)b * S_ + shalf * 256 + tid] =
        (v < -1e29f) ? 0.0f : 1.0f / (1.0f + expf(-(v + bias)));
  }
}

extern "C" void kernel_launch(void* const* d_in, const int* in_sizes, int n_in,
                              void* d_out, int out_size, void* d_ws, size_t ws_size,
                              hipStream_t stream) {
  const float* ue = (const float*)d_in[0];
  const float* ve = (const float*)d_in[1];
  const float* cw = (const float*)d_in[2];
  const float* mask = (const float*)d_in[3];
  const float* pw = (const float*)d_in[4];
  const float* pb = (const float*)d_in[5];
  float* out = (float*)d_out;

  hipLaunchKernelGGL(fused_kernel, dim3(2 * B_), dim3(1024), 0, stream,
                     ue, ve, cw, mask, pw, pb, out);
}

// Round 12
// 17.491 us; speedup vs baseline: 1.4511x; 1.1003x over previous
//
#include <hip/hip_runtime.h>
#include <hip/hip_bf16.h>
#include <math.h>

#define B_ 128
#define S_ 512
#define E_ 64
#define PAD_ 72  // bf16/row in LDS; 36-dword row stride keeps DS ops bank-clean

typedef short bf16x8 __attribute__((ext_vector_type(8)));
typedef float f32x4 __attribute__((ext_vector_type(4)));

__device__ __forceinline__ unsigned short f2b(float f) {
  __hip_bfloat16 h = __float2bfloat16(f);
  unsigned short u;
  __builtin_memcpy(&u, &h, 2);
  return u;
}

// Coalesced 16-row normalize: wave reads rows [rbase, rbase+16) of a [*, 64]
// f32 matrix with 4 fully-contiguous 1KB instructions (lane*16B). Lane holds
// cols [4c,4c+4) of rows i*4+g. Sum-sq reduces over the 16 c-lanes. Scale_i
// supplied per row-quad. Emits bf16 to lds rows [rbase_lds, +16), col 4c.
__device__ __forceinline__ void norm16_coalesced(
    const float* __restrict__ src,  // row rbase, elem 0
    const float* __restrict__ scl,  // per-row numerator: scl[row] or nullptr
    float w0, int c, int g, int lane,
    unsigned short* __restrict__ lds_base) {  // row rbase_lds, elem 0
  f32x4 x[4];
  float sn[4];
#pragma unroll
  for (int i = 0; i < 4; ++i) x[i] = *(const f32x4*)(src + i * 256 + lane * 4);
#pragma unroll
  for (int i = 0; i < 4; ++i)
    sn[i] = scl ? scl[i * 4 + g] * w0 : 1.0f;
#pragma unroll
  for (int i = 0; i < 4; ++i) {
    float ss = x[i][0] * x[i][0] + x[i][1] * x[i][1] +
               x[i][2] * x[i][2] + x[i][3] * x[i][3];
    ss += __shfl_xor(ss, 1); ss += __shfl_xor(ss, 2);
    ss += __shfl_xor(ss, 4); ss += __shfl_xor(ss, 8);
    float s = sn[i] / fmaxf(sqrtf(ss), 1e-7f);
    ushort4 o;
    o.x = f2b(x[i][0] * s); o.y = f2b(x[i][1] * s);
    o.z = f2b(x[i][2] * s); o.w = f2b(x[i][3] * s);
    *(ushort4*)(lds_base + (size_t)(i * 4 + g) * PAD_ + c * 4) = o;
  }
}

// Fused, 256 blocks x 1024 thr (16 waves), 1 block/CU. Block = (batch, shalf).
// Staggered-half V (own half from HBM, other half issued AFTER barrier#1 so
// the barrier's vmcnt(0) drain can't eat the overlap; sibling's L2 lines serve
// it under phase-2a). Coalesced phase-1 loads. [r9 champion, 17.6us measured]
__global__ __launch_bounds__(1024) void fused_kernel(
    const float* __restrict__ ue, const float* __restrict__ ve,
    const float* __restrict__ cw, const float* __restrict__ mask,
    const float* __restrict__ pw, const float* __restrict__ pb,
    float* __restrict__ out) {
  __shared__ unsigned short vlds[S_ * PAD_];   // 73728 B
  __shared__ unsigned short ulds[256 * PAD_];  // 36864 B
  __shared__ float comb[4][256];               // 4096 B

  // bijective swizzle: sibling blocks (same b, shalf 0/1) share an XCD (bx%8)
  const int bx = blockIdx.x;
  const int b = (bx & 7) * 16 + (bx >> 4);
  const int shalf = (bx >> 3) & 1;

  const int tid = threadIdx.x;
  const int wv = tid >> 6;  // 16 waves
  const int lane = tid & 63;
  const int c = lane & 15;
  const int g = lane >> 4;
  const int ws = wv >> 2;  // s-split (0..3): 64 s-rows
  const int wn = wv & 3;   // n-split (0..3): 4 n-tiles per half

  const float w0 = pw[0];
  const float* __restrict__ vb = ve + (size_t)b * S_ * E_;
  const float* __restrict__ cwb = cw + (size_t)b * S_;
  const float* __restrict__ ub = ue + ((size_t)b * S_ + shalf * 256) * E_;
  const float* __restrict__ mb = mask + (size_t)b * S_;

  const int vown = shalf * 256 + wv * 16;        // own-half V row base
  const int voth = (1 - shalf) * 256 + wv * 16;  // other-half base
  const int urow = wv * 16;                      // U row base

  float pen[8];  // own tiles then other tiles, this wave's columns
#pragma unroll
  for (int j = 0; j < 4; ++j) {
    pen[j] = (mb[(shalf * 16 + wn * 4 + j) * 16 + c] > 0.5f) ? 0.0f : -1e30f;
    pen[4 + j] =
        (mb[((1 - shalf) * 16 + wn * 4 + j) * 16 + c] > 0.5f) ? 0.0f : -1e30f;
  }

  // ---- Phase 1: own-half V + U, coalesced ----
  norm16_coalesced(vb + (size_t)vown * E_, cwb + vown, w0, c, g, lane,
                   vlds + (size_t)vown * PAD_);
  norm16_coalesced(ub + (size_t)urow * E_, nullptr, 1.0f, c, g, lane,
                   ulds + (size_t)urow * PAD_);

  __syncthreads();  // barrier #1: own V-half + U ready

  // ---- Other-half V: issue loads now (fly under phase-2a) ----
  const float* psrc = vb + (size_t)voth * E_;
  f32x4 y[4];
#pragma unroll
  for (int i = 0; i < 4; ++i) y[i] = *(const f32x4*)(psrc + i * 256 + lane * 4);
  float cwo[4];
#pragma unroll
  for (int i = 0; i < 4; ++i) cwo[i] = cwb[voth + i * 4 + g];

  // ---- A-fragments from ulds ----
  const unsigned short* urp = ulds + (size_t)(ws * 64 + c) * PAD_ + g * 8;
  bf16x8 a[4][2];
#pragma unroll
  for (int st = 0; st < 4; ++st) {
    a[st][0] = *(const bf16x8*)(urp + st * 16 * PAD_);
    a[st][1] = *(const bf16x8*)(urp + st * 16 * PAD_ + 32);
  }

  float r[4][4];
#pragma unroll
  for (int st = 0; st < 4; ++st)
#pragma unroll
    for (int i = 0; i < 4; ++i) r[st][i] = -INFINITY;

  // ---- Phase-2a: scan OWN half ----
#pragma unroll
  for (int j = 0; j < 4; ++j) {
    const int it = shalf * 16 + wn * 4 + j;
    const unsigned short* vr = vlds + (size_t)(it * 16 + c) * PAD_ + g * 8;
    bf16x8 b0 = *(const bf16x8*)(vr);
    bf16x8 b1 = *(const bf16x8*)(vr + 32);
    f32x4 ci = {pen[j], pen[j], pen[j], pen[j]};
#pragma unroll
    for (int st = 0; st < 4; ++st) {
      f32x4 acc = __builtin_amdgcn_mfma_f32_16x16x32_bf16(a[st][0], b0, ci, 0, 0, 0);
      acc = __builtin_amdgcn_mfma_f32_16x16x32_bf16(a[st][1], b1, acc, 0, 0, 0);
      r[st][0] = fmaxf(r[st][0], acc[0]);
      r[st][1] = fmaxf(r[st][1], acc[1]);
      r[st][2] = fmaxf(r[st][2], acc[2]);
      r[st][3] = fmaxf(r[st][3], acc[3]);
    }
  }

  // ---- Normalize other-half V -> LDS (loads already in flight) ----
#pragma unroll
  for (int i = 0; i < 4; ++i) {
    float ss = y[i][0] * y[i][0] + y[i][1] * y[i][1] +
               y[i][2] * y[i][2] + y[i][3] * y[i][3];
    ss += __shfl_xor(ss, 1); ss += __shfl_xor(ss, 2);
    ss += __shfl_xor(ss, 4); ss += __shfl_xor(ss, 8);
    float s = (w0 * cwo[i]) / fmaxf(sqrtf(ss), 1e-7f);
    ushort4 o;
    o.x = f2b(y[i][0] * s); o.y = f2b(y[i][1] * s);
    o.z = f2b(y[i][2] * s); o.w = f2b(y[i][3] * s);
    *(ushort4*)(vlds + (size_t)(voth + i * 4 + g) * PAD_ + c * 4) = o;
  }

  __syncthreads();  // barrier #2: other V-half ready

  // ---- Phase-2b: scan OTHER half ----
#pragma unroll
  for (int j = 0; j < 4; ++j) {
    const int it = (1 - shalf) * 16 + wn * 4 + j;
    const unsigned short* vr = vlds + (size_t)(it * 16 + c) * PAD_ + g * 8;
    bf16x8 b0 = *(const bf16x8*)(vr);
    bf16x8 b1 = *(const bf16x8*)(vr + 32);
    f32x4 ci = {pen[4 + j], pen[4 + j], pen[4 + j], pen[4 + j]};
#pragma unroll
    for (int st = 0; st < 4; ++st) {
      f32x4 acc = __builtin_amdgcn_mfma_f32_16x16x32_bf16(a[st][0], b0, ci, 0, 0, 0);
      acc = __builtin_amdgcn_mfma_f32_16x16x32_bf16(a[st][1], b1, acc, 0, 0, 0);
      r[st][0] = fmaxf(r[st][0], acc[0]);
      r[st][1] = fmaxf(r[st][1], acc[1]);
      r[st][2] = fmaxf(r[st][2], acc[2]);
      r[st][3] = fmaxf(r[st][3], acc[3]);
    }
  }

  // ---- Reduce over 16 column-lanes ----
#pragma unroll
  for (int st = 0; st < 4; ++st)
#pragma unroll
    for (int i = 0; i < 4; ++i) {
      float v = r[st][i];
      v = fmaxf(v, __shfl_xor(v, 1)); v = fmaxf(v, __shfl_xor(v, 2));
      v = fmaxf(v, __shfl_xor(v, 4)); v = fmaxf(v, __shfl_xor(v, 8));
      r[st][i] = v;
    }

  if (c == 0) {
#pragma unroll
    for (int st = 0; st < 4; ++st)
#pragma unroll
      for (int i = 0; i < 4; ++i)
        comb[wn][ws * 64 + st * 16 + g * 4 + i] = r[st][i];
  }

  __syncthreads();  // barrier #3

  if (tid < 256) {
    float v = fmaxf(fmaxf(comb[0][tid], comb[1][tid]),
                    fmaxf(comb[2][tid], comb[3][tid]));
    float bias = pb[0];
    out[(size_t)b * S_ + shalf * 256 + tid] =
        (v < -1e29f) ? 0.0f : 1.0f / (1.0f + expf(-(v + bias)));
  }
}

extern "C" void kernel_launch(void* const* d_in, const int* in_sizes, int n_in,
                              void* d_out, int out_size, void* d_ws, size_t ws_size,
                              hipStream_t stream) {
  const float* ue = (const float*)d_in[0];
  const float* ve = (const float*)d_in[1];
  const float* cw = (const float*)d_in[2];
  const float* mask = (const float*)d_in[3];
  const float* pw = (const float*)d_in[4];
  const float* pb = (const float*)d_in[5];
  float* out = (float*)d_out;

  hipLaunchKernelGGL(fused_kernel, dim3(2 * B_), dim3(1024), 0, stream,
                     ue, ve, cw, mask, pw, pb, out);
}